// Round 6
// baseline (598.285 us; speedup 1.0000x reference)
//
#include <hip/hip_runtime.h>
#include <math.h>

#define B_ROWS 32768
#define D_DIM  256
#define K_CODES 2048

// d_out layout (float elements), reference return order:
// quantized_st [B,D], vq_loss, entropy, encoding_inds [B,1], cluster_metric
#define OUT_Q   0
#define OUT_VQ  8388608
#define OUT_ENT 8388609
#define OUT_IND 8388610
#define OUT_CM  8421378

// A_cat [32768][512] fp16 = 33.55 MB lives in the d_out Q region (exact fit);
// k_gather overwrites it with the real output afterwards.

// ws layout (bytes)
#define WS_SE2   0          // 2048 float
#define WS_SX2   8192       // 32768 float
#define WS_CNT   139264     // 2048 int   (zeroed in k_init)
#define WS_PACK  147456     // 32768 u64  (set to ~0 in k_init)
#define WS_MSEP  409600     // 8192 double
#define WS_DISTP 475136     // 8192 double
#define WS_BCAT  540672     // 2048 x 768 fp16 = 3 MB

typedef _Float16 f16x8 __attribute__((ext_vector_type(8)));
typedef float f32x4 __attribute__((ext_vector_type(4)));
typedef union { _Float16 h[4]; uint2 u2; } h4pack;

// ---------------------------------------------------------------------------
// Fused init (unchanged).
__global__ __launch_bounds__(256) void k_init(
    const float* __restrict__ X, const float* __restrict__ E,
    _Float16* __restrict__ A, _Float16* __restrict__ Bc,
    float* __restrict__ sx2, float* __restrict__ se2,
    unsigned long long* __restrict__ packed, int* __restrict__ counts) {
  int w = threadIdx.x >> 6, lane = threadIdx.x & 63;
  if (blockIdx.x < 8192) {
    int row = blockIdx.x * 4 + w;
    float4 v = ((const float4*)(X + (size_t)row * D_DIM))[lane];
    float s = v.x * v.x + v.y * v.y + v.z * v.z + v.w * v.w;
#pragma unroll
    for (int off = 32; off > 0; off >>= 1) s += __shfl_xor(s, off, 64);
    if (lane == 0) { sx2[row] = s; packed[row] = ~0ull; }
    h4pack hi, lo;
    hi.h[0] = (_Float16)v.x; hi.h[1] = (_Float16)v.y;
    hi.h[2] = (_Float16)v.z; hi.h[3] = (_Float16)v.w;
    lo.h[0] = (_Float16)((v.x - (float)hi.h[0]) * 4096.0f);
    lo.h[1] = (_Float16)((v.y - (float)hi.h[1]) * 4096.0f);
    lo.h[2] = (_Float16)((v.z - (float)hi.h[2]) * 4096.0f);
    lo.h[3] = (_Float16)((v.w - (float)hi.h[3]) * 4096.0f);
    *(uint2*)&A[(size_t)row * 512 + 4 * lane] = hi.u2;
    *(uint2*)&A[(size_t)row * 512 + 256 + 4 * lane] = lo.u2;
  } else {
    int bb = blockIdx.x - 8192;
    int row = bb * 4 + w;
    if (threadIdx.x < 4) counts[bb * 4 + threadIdx.x] = 0;
    float4 v = ((const float4*)(E + (size_t)row * D_DIM))[lane];
    float s = v.x * v.x + v.y * v.y + v.z * v.z + v.w * v.w;
#pragma unroll
    for (int off = 32; off > 0; off >>= 1) s += __shfl_xor(s, off, 64);
    if (lane == 0) se2[row] = s;
    const float S = 4194304.0f;       // 2^22
    const float SH = 0.000244140625f; // 2^-12
    float e0 = v.x * S, e1 = v.y * S, e2 = v.z * S, e3 = v.w * S;
    h4pack b1, b2, b3;
    b1.h[0] = (_Float16)e0; b1.h[1] = (_Float16)e1;
    b1.h[2] = (_Float16)e2; b1.h[3] = (_Float16)e3;
    b2.h[0] = (_Float16)((float)b1.h[0] * SH);
    b2.h[1] = (_Float16)((float)b1.h[1] * SH);
    b2.h[2] = (_Float16)((float)b1.h[2] * SH);
    b2.h[3] = (_Float16)((float)b1.h[3] * SH);
    b3.h[0] = (_Float16)(e0 - (float)b1.h[0]);
    b3.h[1] = (_Float16)(e1 - (float)b1.h[1]);
    b3.h[2] = (_Float16)(e2 - (float)b1.h[2]);
    b3.h[3] = (_Float16)(e3 - (float)b1.h[3]);
    *(uint2*)&Bc[(size_t)row * 768 + 4 * lane] = b1.u2;
    *(uint2*)&Bc[(size_t)row * 768 + 256 + 4 * lane] = b2.u2;
    *(uint2*)&Bc[(size_t)row * 768 + 512 + 4 * lane] = b3.u2;
  }
}

// ---------------------------------------------------------------------------
// 256x256-tile MFMA GEMM + argmin.  Round-6: r4's race-fixed 1-barrier/tile
// free-run structure + WAVE STAGGER.  Each SIMD hosts one wm=0 and one wm=1
// wave (waves 0-3 / 4-7); three lockstep schedules (r0/r1/r4) all measured
// 26-30% MfmaUtil because all 8 waves read LDS simultaneously then MFMA
// simultaneously (pipes alternate, never co-busy).  Fix: wm=1 waves run the
// quad sequence in OPPOSITE order (i-hi half first), so each SIMD's wave
// pair is read-phase vs MFMA-phase shifted -> LDS pipe and matrix pipe
// overlap.  Per-fragment MFMA k-order unchanged -> bit-exact accumulation.
// Boundary: per-wave vmcnt(0) BEFORE s_barrier (r4 ordering; vmcnt is
// per-wave, so wait-after-barrier would race other waves' LDS-DMA).
#define BAR()  __builtin_amdgcn_s_barrier()
#define SB0()  __builtin_amdgcn_sched_barrier(0)
#define WLGKM(n)                                                 \
  do {                                                           \
    asm volatile("s_waitcnt lgkmcnt(" #n ")" ::: "memory");      \
    SB0();                                                       \
  } while (0)
#define DSR(dst, a, o) \
  asm volatile("ds_read_b128 %0, %1 offset:" o : "=v"(dst) : "v"(a))

#define MFMA_QUAD(I0, J0, AF, BF)                                            \
  do {                                                                       \
    __builtin_amdgcn_s_setprio(1);                                           \
    _Pragma("unroll") for (int ii = 0; ii < 4; ++ii) {                       \
      _Pragma("unroll") for (int jj = 0; jj < 2; ++jj) {                     \
        _Pragma("unroll") for (int kk = 0; kk < 2; ++kk) {                   \
          acc[(I0) + ii][(J0) + jj] =                                        \
              __builtin_amdgcn_mfma_f32_16x16x32_f16(                        \
                  (AF)[ii * 2 + kk], (BF)[jj * 2 + kk],                      \
                  acc[(I0) + ii][(J0) + jj], 0, 0, 0);                       \
        }                                                                    \
      }                                                                      \
    }                                                                        \
    __builtin_amdgcn_s_setprio(0);                                           \
  } while (0)

__global__ __launch_bounds__(512, 2) void k_mfma2(
    const _Float16* __restrict__ A, const _Float16* __restrict__ Bc,
    const float* __restrict__ se2, const float* __restrict__ sx2,
    unsigned long long* __restrict__ packed) {
  extern __shared__ char smem[];  // 131072 B
  const int tid = threadIdx.x;
  const int w = tid >> 6, lane = tid & 63;
  const int wm = w >> 2, wn = w & 3;     // wave tile: rows wm*128, cols wn*64
  const int q = lane >> 4, c = lane & 15;
  const int rowb = blockIdx.x & 127, colb = blockIdx.x >> 7;
  const int rowpan = rowb * 256, colpan = colb * 256;
  const int rsel = lane >> 3;                      // staging: row-within-8
  const int chunkb = ((lane & 7) ^ rsel) * 16;     // inverse-swizzled src 16B
  const int rswz = c & 7;                          // read-side swizzle key

  const char* Abase = (const char*)A;
  const char* Bbase = (const char*)Bc;

  // g->(hh,ss): 0:A(0,0) 1:B(0,0) 2:B(0,1) 3:B(1,0) 4:B(1,1) 5:A(1,0)
  // 6:A(0,1) 7:A(1,1)
  auto issue = [&](int tt, int g, int bsel) {
    const int hh = (g == 3 || g == 4 || g == 5 || g == 7) ? 1 : 0;
    const int ss = (g == 2 || g == 4 || g == 6 || g == 7) ? 1 : 0;
    const int rl = hh * 128 + ss * 64 + w * 8 + rsel;
    const char* src;
    char* dst;
    if (g == 0 || g >= 5) {
      // A k-map (bytes/row of 1024): t<4 -> hi, 4..7 -> lo, 8..11 -> hi again
      int aoff = (tt & 3) * 128 + (((tt >> 2) == 1) ? 512 : 0);
      src = Abase + ((size_t)(rowpan + rl) << 10) + aoff + chunkb;
      dst = smem + bsel * 32768 + hh * 16384 + ss * 8192 + w * 1024;
    } else {
      src = Bbase + (size_t)(colpan + rl) * 1536 + tt * 128 + chunkb;
      dst = smem + 65536 + bsel * 32768 + hh * 16384 + ss * 8192 + w * 1024;
    }
    __builtin_amdgcn_global_load_lds(
        (const __attribute__((address_space(1))) unsigned int*)src,
        (__attribute__((address_space(3))) unsigned int*)dst, 16, 0, 0);
  };

  f32x4 acc[8][4];
#pragma unroll
  for (int i = 0; i < 8; ++i)
#pragma unroll
    for (int j = 0; j < 4; ++j) acc[i][j] = (f32x4){0.f, 0.f, 0.f, 0.f};

  // per-lane LDS byte addresses for asm ds_read_b128 (swizzled slots)
  const unsigned ldsA = (unsigned)(uintptr_t)smem + (unsigned)((wm * 128 + c) * 128);
  const unsigned ldsB = (unsigned)(uintptr_t)smem + 65536u +
                        (unsigned)((wn * 64 + c) * 128);
  const unsigned sl0 = (unsigned)(((0 * 4 + q) ^ rswz) * 16);
  const unsigned sl1 = (unsigned)(((1 * 4 + q) ^ rswz) * 16);

  // prologue: stage tile 0 fully, drain own DMA, publish via barrier
#pragma unroll
  for (int g = 0; g < 8; ++g) issue(0, g, 0);
  asm volatile("s_waitcnt vmcnt(0)" ::: "memory");
  BAR();

  f16x8 af[8], bf01[4], bf23[4];

#pragma unroll 2
  for (int t = 0; t < 12; ++t) {
    const int bsel = t & 1;
    const bool pre = (t < 11);
    const unsigned aA0 = ldsA + (unsigned)(bsel * 32768) + sl0;
    const unsigned aA1 = ldsA + (unsigned)(bsel * 32768) + sl1;
    const unsigned aB0 = ldsB + (unsigned)(bsel * 32768) + sl0;
    const unsigned aB1 = ldsB + (unsigned)(bsel * 32768) + sl1;

    // all 8 DMA issues for t+1 at tile start -> full tile of latency slack
    if (pre) {
#pragma unroll
      for (int g = 0; g < 8; ++g) issue(t + 1, g, bsel ^ 1);
    }

    if (wm == 0) {
      // ---- forward order: i-lo quads first ----
      DSR(af[0], aA0, "0");    DSR(af[1], aA1, "0");
      DSR(af[2], aA0, "2048"); DSR(af[3], aA1, "2048");
      DSR(af[4], aA0, "4096"); DSR(af[5], aA1, "4096");
      DSR(af[6], aA0, "6144"); DSR(af[7], aA1, "6144");
      DSR(bf01[0], aB0, "0");    DSR(bf01[1], aB1, "0");
      DSR(bf01[2], aB0, "2048"); DSR(bf01[3], aB1, "2048");
      DSR(bf23[0], aB0, "4096"); DSR(bf23[1], aB1, "4096");
      DSR(bf23[2], aB0, "6144"); DSR(bf23[3], aB1, "6144");

      WLGKM(4);                 // af + bf01 resident (bf23 may still fly)
      MFMA_QUAD(0, 0, af, bf01);
      WLGKM(0);                 // bf23 resident (drained under Q00's MFMAs)
      MFMA_QUAD(0, 2, af, bf23);

      DSR(af[0], aA0, "8192");  DSR(af[1], aA1, "8192");
      DSR(af[2], aA0, "10240"); DSR(af[3], aA1, "10240");
      DSR(af[4], aA0, "12288"); DSR(af[5], aA1, "12288");
      DSR(af[6], aA0, "14336"); DSR(af[7], aA1, "14336");
      WLGKM(0);
      MFMA_QUAD(4, 2, af, bf23);
      MFMA_QUAD(4, 0, af, bf01);
    } else {
      // ---- staggered order: i-hi quads first (SIMD partner wave is in the
      // opposite phase -> LDS pipe and matrix pipe co-busy) ----
      DSR(af[0], aA0, "8192");  DSR(af[1], aA1, "8192");
      DSR(af[2], aA0, "10240"); DSR(af[3], aA1, "10240");
      DSR(af[4], aA0, "12288"); DSR(af[5], aA1, "12288");
      DSR(af[6], aA0, "14336"); DSR(af[7], aA1, "14336");
      DSR(bf23[0], aB0, "4096"); DSR(bf23[1], aB1, "4096");
      DSR(bf23[2], aB0, "6144"); DSR(bf23[3], aB1, "6144");
      DSR(bf01[0], aB0, "0");    DSR(bf01[1], aB1, "0");
      DSR(bf01[2], aB0, "2048"); DSR(bf01[3], aB1, "2048");

      WLGKM(4);                 // af(s1) + bf23 resident (bf01 may still fly)
      MFMA_QUAD(4, 2, af, bf23);
      WLGKM(0);                 // bf01 resident
      MFMA_QUAD(4, 0, af, bf01);

      DSR(af[0], aA0, "0");    DSR(af[1], aA1, "0");
      DSR(af[2], aA0, "2048"); DSR(af[3], aA1, "2048");
      DSR(af[4], aA0, "4096"); DSR(af[5], aA1, "4096");
      DSR(af[6], aA0, "6144"); DSR(af[7], aA1, "6144");
      WLGKM(0);
      MFMA_QUAD(0, 0, af, bf01);
      MFMA_QUAD(0, 2, af, bf23);
    }

    // boundary: drain OWN DMA first, then barrier publishes all waves'
    // LDS-DMA writes (wait-before-barrier; wait-after was r3's race).
    if (pre) {
      asm volatile("s_waitcnt vmcnt(0)" ::: "memory");
      BAR();
    }
  }

  __syncthreads();  // full fence before epilogue LDS reuse

  // ---- epilogue: identical dist math / tie rules as previous kernel ----
  const float inv = 4.76837158203125e-07f;  // 2^-21, exact pow2
  float se_j[4];
#pragma unroll
  for (int j = 0; j < 4; ++j) se_j[j] = se2[colpan + wn * 64 + j * 16 + c];
  unsigned long long* m = (unsigned long long*)smem;  // [4][256], reuse LDS
#pragma unroll
  for (int i = 0; i < 8; ++i) {
    float4 sx4 = *(const float4*)&sx2[rowpan + wm * 128 + i * 16 + q * 4];
#pragma unroll
    for (int r = 0; r < 4; ++r) {
      float sx = ((const float*)&sx4)[r];
      float bs = 3.402823466e38f;
      int bk = 0;
#pragma unroll
      for (int j = 0; j < 4; ++j) {  // ascending j -> ascending code
        float t1 = sx + se_j[j];            // fp32 round 1 (matches ref)
        float d = t1 - acc[i][j][r] * inv;  // exact mul, fp32 round 2
        if (d < bs) { bs = d; bk = colpan + wn * 64 + j * 16 + c; }
      }
#pragma unroll
      for (int off = 1; off < 16; off <<= 1) {  // reduce over c (q kept)
        float os = __shfl_xor(bs, off, 64);
        int ok = __shfl_xor(bk, off, 64);
        if (os < bs || (os == bs && ok < bk)) { bs = os; bk = ok; }
      }
      if (c == 0) {
        m[wn * 256 + wm * 128 + i * 16 + q * 4 + r] =
            ((unsigned long long)__float_as_uint(bs) << 32) |
            (unsigned long long)(unsigned int)bk;
      }
    }
  }
  __syncthreads();
  if (tid < 256) {  // merge 4 wn-candidates; u64 min == (min d, then min k)
    unsigned long long v = m[tid];
#pragma unroll
    for (int mm = 1; mm < 4; ++mm) {
      unsigned long long o = m[mm * 256 + tid];
      if (o < v) v = o;
    }
    atomicMin(&packed[rowpan + tid], v);
  }
}

// ---------------------------------------------------------------------------
// Unpack winner per row, histogram, gather codebook rows, STE output,
// per-wave double partials.  (r4 version restored: the r5 last-block fusion's
// per-block __threadfence = device-scope L2 writeback on non-coherent XCD
// L2s -> k_gather went 35 -> 262 us.  Separate 1-block k_final is cheaper.)
__global__ __launch_bounds__(256) void k_gather(
    const float* __restrict__ X, const float* __restrict__ E,
    const unsigned long long* __restrict__ packed, float* __restrict__ outq,
    float* __restrict__ out_ind, int* __restrict__ counts,
    double* __restrict__ msep, double* __restrict__ distp) {
  __shared__ int sk[16];
  __shared__ float sd[16];
  int tid = threadIdx.x;
  if (tid < 16) {
    int row = blockIdx.x * 16 + tid;
    unsigned long long v = packed[row];
    int k = (int)(v & 0xFFFFFFFFull);
    sk[tid] = k;
    sd[tid] = __uint_as_float((unsigned int)(v >> 32));
    out_ind[row] = (float)k;
    atomicAdd(&counts[k], 1);
  }
  __syncthreads();
  int wave = tid >> 6, lane = tid & 63;
  double msum = 0.0, dsum = 0.0;
#pragma unroll
  for (int rr = 0; rr < 4; rr++) {
    int li = wave * 4 + rr;
    int b = blockIdx.x * 16 + li;
    int ind = sk[li];
    float4 x4 = ((const float4*)(X + (size_t)b * D_DIM))[lane];
    float4 q4 = ((const float4*)(E + (size_t)ind * D_DIM))[lane];
    float d0 = q4.x - x4.x, d1 = q4.y - x4.y, d2 = q4.z - x4.z, d3 = q4.w - x4.w;
    float4 o;
    o.x = x4.x + d0; o.y = x4.y + d1; o.z = x4.z + d2; o.w = x4.w + d3;
    ((float4*)(outq + (size_t)b * D_DIM))[lane] = o;
    float v = d0 * d0 + d1 * d1 + d2 * d2 + d3 * d3;
#pragma unroll
    for (int off = 32; off > 0; off >>= 1) v += __shfl_xor(v, off, 64);
    if (lane == 0) { msum += (double)v; dsum += (double)sd[li]; }
  }
  if (lane == 0) {
    int wg = blockIdx.x * 4 + wave;
    msep[wg] = msum;
    distp[wg] = dsum;
  }
}

// ---------------------------------------------------------------------------
__global__ __launch_bounds__(256) void k_final(
    const int* __restrict__ counts, const double* __restrict__ msep,
    const double* __restrict__ distp, float* __restrict__ out) {
  __shared__ double red[256];
  int t = threadIdx.x;

  double m = 0.0;
  for (int i = t; i < 8192; i += 256) m += msep[i];
  red[t] = m;
  __syncthreads();
  for (int s = 128; s > 0; s >>= 1) {
    if (t < s) red[t] += red[t + s];
    __syncthreads();
  }
  if (t == 0) {
    double mse = red[0] / ((double)B_ROWS * (double)D_DIM);
    out[OUT_VQ] = (float)(mse * 1.25);  // 0.25*commit + embed
  }
  __syncthreads();

  double d = 0.0;
  for (int i = t; i < 8192; i += 256) d += distp[i];
  red[t] = d;
  __syncthreads();
  for (int s = 128; s > 0; s >>= 1) {
    if (t < s) red[t] += red[t + s];
    __syncthreads();
  }
  if (t == 0) out[OUT_CM] = (float)(red[0] / (double)B_ROWS);
  __syncthreads();

  double e = 0.0;
  for (int k = t; k < K_CODES; k += 256) {
    float p = (float)counts[k] * (1.0f / 32768.0f);
    e += (double)(p * logf(p + 1e-10f));
  }
  red[t] = e;
  __syncthreads();
  for (int s = 128; s > 0; s >>= 1) {
    if (t < s) red[t] += red[t + s];
    __syncthreads();
  }
  if (t == 0) out[OUT_ENT] = (float)(-red[0]);
}

// ---------------------------------------------------------------------------
extern "C" void kernel_launch(void* const* d_in, const int* in_sizes, int n_in,
                              void* d_out, int out_size, void* d_ws,
                              size_t ws_size, hipStream_t stream) {
  const float* X = (const float*)d_in[0];  // latents [32768,256]
  const float* E = (const float*)d_in[1];  // embedding [2048,256]
  float* out = (float*)d_out;
  char* ws = (char*)d_ws;
  float* se2 = (float*)(ws + WS_SE2);
  float* sx2 = (float*)(ws + WS_SX2);
  int* counts = (int*)(ws + WS_CNT);
  unsigned long long* packed = (unsigned long long*)(ws + WS_PACK);
  double* msep = (double*)(ws + WS_MSEP);
  double* distp = (double*)(ws + WS_DISTP);
  _Float16* Bcat = (_Float16*)(ws + WS_BCAT);
  _Float16* Acat = (_Float16*)d_out;  // Q region; k_gather overwrites later

  static bool attr_done = false;
  if (!attr_done) {  // allow 128 KiB dynamic LDS for k_mfma2
    hipFuncSetAttribute((const void*)k_mfma2,
                        hipFuncAttributeMaxDynamicSharedMemorySize, 131072);
    attr_done = true;
  }

  k_init<<<8704, 256, 0, stream>>>(X, E, Acat, Bcat, sx2, se2, packed, counts);
  k_mfma2<<<1024, 512, 131072, stream>>>(Acat, Bcat, se2, sx2, packed);
  k_gather<<<B_ROWS / 16, 256, 0, stream>>>(X, E, packed, out + OUT_Q,
                                            out + OUT_IND, counts, msep, distp);
  k_final<<<1, 256, 0, stream>>>(counts, msep, distp, out);
}

// Round 7
// 271.520 us; speedup vs baseline: 2.2035x; 2.2035x over previous
//
#include <hip/hip_runtime.h>
#include <math.h>

#define B_ROWS 32768
#define D_DIM  256
#define K_CODES 2048

// d_out layout (float elements), reference return order:
// quantized_st [B,D], vq_loss, entropy, encoding_inds [B,1], cluster_metric
#define OUT_Q   0
#define OUT_VQ  8388608
#define OUT_ENT 8388609
#define OUT_IND 8388610
#define OUT_CM  8421378

// A_cat [32768][512] fp16 = 33.55 MB lives in the d_out Q region (exact fit);
// k_gather overwrites it with the real output afterwards.

// ws layout (bytes)
#define WS_SE2   0          // 2048 float
#define WS_SX2   8192       // 32768 float
#define WS_CNT   139264     // 2048 int   (zeroed in k_init)
#define WS_PACK  147456     // 32768 u64  (set to ~0 in k_init)
#define WS_MSEP  409600     // 8192 double
#define WS_DISTP 475136     // 8192 double
#define WS_BCAT  540672     // 2048 x 768 fp16 = 3 MB

typedef _Float16 f16x8 __attribute__((ext_vector_type(8)));
typedef float f32x4 __attribute__((ext_vector_type(4)));
typedef union { _Float16 h[4]; uint2 u2; } h4pack;

// ---------------------------------------------------------------------------
// Fused init (unchanged).
__global__ __launch_bounds__(256) void k_init(
    const float* __restrict__ X, const float* __restrict__ E,
    _Float16* __restrict__ A, _Float16* __restrict__ Bc,
    float* __restrict__ sx2, float* __restrict__ se2,
    unsigned long long* __restrict__ packed, int* __restrict__ counts) {
  int w = threadIdx.x >> 6, lane = threadIdx.x & 63;
  if (blockIdx.x < 8192) {
    int row = blockIdx.x * 4 + w;
    float4 v = ((const float4*)(X + (size_t)row * D_DIM))[lane];
    float s = v.x * v.x + v.y * v.y + v.z * v.z + v.w * v.w;
#pragma unroll
    for (int off = 32; off > 0; off >>= 1) s += __shfl_xor(s, off, 64);
    if (lane == 0) { sx2[row] = s; packed[row] = ~0ull; }
    h4pack hi, lo;
    hi.h[0] = (_Float16)v.x; hi.h[1] = (_Float16)v.y;
    hi.h[2] = (_Float16)v.z; hi.h[3] = (_Float16)v.w;
    lo.h[0] = (_Float16)((v.x - (float)hi.h[0]) * 4096.0f);
    lo.h[1] = (_Float16)((v.y - (float)hi.h[1]) * 4096.0f);
    lo.h[2] = (_Float16)((v.z - (float)hi.h[2]) * 4096.0f);
    lo.h[3] = (_Float16)((v.w - (float)hi.h[3]) * 4096.0f);
    *(uint2*)&A[(size_t)row * 512 + 4 * lane] = hi.u2;
    *(uint2*)&A[(size_t)row * 512 + 256 + 4 * lane] = lo.u2;
  } else {
    int bb = blockIdx.x - 8192;
    int row = bb * 4 + w;
    if (threadIdx.x < 4) counts[bb * 4 + threadIdx.x] = 0;
    float4 v = ((const float4*)(E + (size_t)row * D_DIM))[lane];
    float s = v.x * v.x + v.y * v.y + v.z * v.z + v.w * v.w;
#pragma unroll
    for (int off = 32; off > 0; off >>= 1) s += __shfl_xor(s, off, 64);
    if (lane == 0) se2[row] = s;
    const float S = 4194304.0f;       // 2^22
    const float SH = 0.000244140625f; // 2^-12
    float e0 = v.x * S, e1 = v.y * S, e2 = v.z * S, e3 = v.w * S;
    h4pack b1, b2, b3;
    b1.h[0] = (_Float16)e0; b1.h[1] = (_Float16)e1;
    b1.h[2] = (_Float16)e2; b1.h[3] = (_Float16)e3;
    b2.h[0] = (_Float16)((float)b1.h[0] * SH);
    b2.h[1] = (_Float16)((float)b1.h[1] * SH);
    b2.h[2] = (_Float16)((float)b1.h[2] * SH);
    b2.h[3] = (_Float16)((float)b1.h[3] * SH);
    b3.h[0] = (_Float16)(e0 - (float)b1.h[0]);
    b3.h[1] = (_Float16)(e1 - (float)b1.h[1]);
    b3.h[2] = (_Float16)(e2 - (float)b1.h[2]);
    b3.h[3] = (_Float16)(e3 - (float)b1.h[3]);
    *(uint2*)&Bc[(size_t)row * 768 + 4 * lane] = b1.u2;
    *(uint2*)&Bc[(size_t)row * 768 + 256 + 4 * lane] = b2.u2;
    *(uint2*)&Bc[(size_t)row * 768 + 512 + 4 * lane] = b3.u2;
  }
}

// ---------------------------------------------------------------------------
// Round-7: 128x128-tile, 4-wave (256-thr), 64 KB LDS -> 2 BLOCKS PER CU.
// Every 1-block/CU schedule (r0/r1/r2/r4/r5) measured 26-30% MfmaUtil: all
// waves share one barrier, so the CU's LDS-read and MFMA windows alternate.
// With 2 independent blocks per CU (m97's mechanism), one block's waves MFMA
// while the other sits in its boundary drain.  acc shrinks to 64 AGPR
// (per-wave 64x64 out), working ~95 VGPR -> ~160 unified (2 waves/SIMD from
// EACH of 2 blocks).  Same A/B layouts, same inverse-swizzled staging + XOR
// read swizzle (rows still 128 B), same per-fragment 24-step MFMA k-order
// (bit-exact), same packed-u64 atomicMin argmin (16 candidates/row now).
// Free-run r4 schedule; vmcnt(0) BEFORE barrier at the boundary (per-wave
// vmcnt + barrier publish; wait-after-barrier was r3's race).  No setprio
// (m190: hurts non-phase-split GEMM).
#define BAR()  __builtin_amdgcn_s_barrier()
#define SB0()  __builtin_amdgcn_sched_barrier(0)
#define WLGKM(n)                                                 \
  do {                                                           \
    asm volatile("s_waitcnt lgkmcnt(" #n ")" ::: "memory");      \
    SB0();                                                       \
  } while (0)
#define DSR(dst, a, o) \
  asm volatile("ds_read_b128 %0, %1 offset:" o : "=v"(dst) : "v"(a))

__global__ __launch_bounds__(256, 2) void k_mfma2(
    const _Float16* __restrict__ A, const _Float16* __restrict__ Bc,
    const float* __restrict__ se2, const float* __restrict__ sx2,
    unsigned long long* __restrict__ packed) {
  extern __shared__ char smem[];  // 65536 B: A 2x16K | B 2x16K
  const int tid = threadIdx.x;
  const int w = tid >> 6, lane = tid & 63;
  const int wm = w >> 1, wn = w & 1;     // wave tile: rows wm*64, cols wn*64
  const int q = lane >> 4, c = lane & 15;
  const int rowb = blockIdx.x & 255, colb = blockIdx.x >> 8;
  const int rowpan = rowb * 128, colpan = colb * 128;
  const int rsel = lane >> 3;                      // staging: row-within-8
  const int chunkb = ((lane & 7) ^ rsel) * 16;     // inverse-swizzled src 16B
  const int rswz = c & 7;                          // read-side swizzle key

  const char* Abase = (const char*)A;
  const char* Bbase = (const char*)Bc;

  // issue groups: g 0..3 = A rows [g*32, g*32+32); g 4..7 = B rows likewise.
  // Each group: 256 threads x 16 B = 4 KB (32 rows x 128 B), LDS-linear dest,
  // source chunk pre-swizzled (chunkb) so swizzled ds_read sees clean rows.
  auto issue = [&](int tt, int g, int bsel) {
    const int rl = (g & 3) * 32 + w * 8 + rsel;
    const char* src;
    char* dst;
    if (g < 4) {
      // A k-map (bytes/row of 1024): t<4 -> hi, 4..7 -> lo, 8..11 -> hi again
      int aoff = (tt & 3) * 128 + (((tt >> 2) == 1) ? 512 : 0);
      src = Abase + ((size_t)(rowpan + rl) << 10) + aoff + chunkb;
      dst = smem + bsel * 16384 + (g & 3) * 4096 + w * 1024;
    } else {
      src = Bbase + (size_t)(colpan + rl) * 1536 + tt * 128 + chunkb;
      dst = smem + 32768 + bsel * 16384 + (g & 3) * 4096 + w * 1024;
    }
    __builtin_amdgcn_global_load_lds(
        (const __attribute__((address_space(1))) unsigned int*)src,
        (__attribute__((address_space(3))) unsigned int*)dst, 16, 0, 0);
  };

  f32x4 acc[4][4];
#pragma unroll
  for (int i = 0; i < 4; ++i)
#pragma unroll
    for (int j = 0; j < 4; ++j) acc[i][j] = (f32x4){0.f, 0.f, 0.f, 0.f};

  // per-lane LDS byte addresses for asm ds_read_b128 (swizzled slots)
  const unsigned ldsA = (unsigned)(uintptr_t)smem + (unsigned)((wm * 64 + c) * 128);
  const unsigned ldsB = (unsigned)(uintptr_t)smem + 32768u +
                        (unsigned)((wn * 64 + c) * 128);
  const unsigned sl0 = (unsigned)(((0 * 4 + q) ^ rswz) * 16);
  const unsigned sl1 = (unsigned)(((1 * 4 + q) ^ rswz) * 16);

  // prologue: stage tile 0 fully, drain own DMA, publish via barrier
#pragma unroll
  for (int g = 0; g < 8; ++g) issue(0, g, 0);
  asm volatile("s_waitcnt vmcnt(0)" ::: "memory");
  BAR();

  f16x8 af[8], bf01[4], bf23[4];

#pragma unroll 2
  for (int t = 0; t < 12; ++t) {
    const int bsel = t & 1;
    const bool pre = (t < 11);
    const unsigned aA0 = ldsA + (unsigned)(bsel * 16384) + sl0;
    const unsigned aA1 = ldsA + (unsigned)(bsel * 16384) + sl1;
    const unsigned aB0 = ldsB + (unsigned)(bsel * 16384) + sl0;
    const unsigned aB1 = ldsB + (unsigned)(bsel * 16384) + sl1;

    // all 8 DMA issues for t+1 at tile start -> full tile of latency slack
    if (pre) {
#pragma unroll
      for (int g = 0; g < 8; ++g) issue(t + 1, g, bsel ^ 1);
    }

    // read burst: A all 4 i-blocks (8) + B j0..1 (4) + B j2..3 (4)
    DSR(af[0], aA0, "0");    DSR(af[1], aA1, "0");
    DSR(af[2], aA0, "2048"); DSR(af[3], aA1, "2048");
    DSR(af[4], aA0, "4096"); DSR(af[5], aA1, "4096");
    DSR(af[6], aA0, "6144"); DSR(af[7], aA1, "6144");
    DSR(bf01[0], aB0, "0");    DSR(bf01[1], aB1, "0");
    DSR(bf01[2], aB0, "2048"); DSR(bf01[3], aB1, "2048");
    DSR(bf23[0], aB0, "4096"); DSR(bf23[1], aB1, "4096");
    DSR(bf23[2], aB0, "6144"); DSR(bf23[3], aB1, "6144");

    WLGKM(4);  // af + bf01 resident (bf23's 4 may still fly)
#pragma unroll
    for (int ii = 0; ii < 4; ++ii)
#pragma unroll
      for (int jj = 0; jj < 2; ++jj)
#pragma unroll
        for (int kk = 0; kk < 2; ++kk)
          acc[ii][jj] = __builtin_amdgcn_mfma_f32_16x16x32_f16(
              af[ii * 2 + kk], bf01[jj * 2 + kk], acc[ii][jj], 0, 0, 0);
    SB0();
    WLGKM(0);  // bf23 resident (drained under the 16 MFMAs above)
#pragma unroll
    for (int ii = 0; ii < 4; ++ii)
#pragma unroll
      for (int jj = 0; jj < 2; ++jj)
#pragma unroll
        for (int kk = 0; kk < 2; ++kk)
          acc[ii][2 + jj] = __builtin_amdgcn_mfma_f32_16x16x32_f16(
              af[ii * 2 + kk], bf23[jj * 2 + kk], acc[ii][2 + jj], 0, 0, 0);
    SB0();

    // boundary: drain OWN DMA first, then barrier publishes all waves'
    // LDS-DMA writes.  Other resident block on this CU fills the gap.
    if (pre) {
      asm volatile("s_waitcnt vmcnt(0)" ::: "memory");
      BAR();
    }
  }

  __syncthreads();  // full fence before epilogue LDS reuse

  // ---- epilogue: identical dist math / tie rules as previous rounds ----
  const float inv = 4.76837158203125e-07f;  // 2^-21, exact pow2
  float se_j[4];
#pragma unroll
  for (int j = 0; j < 4; ++j) se_j[j] = se2[colpan + wn * 64 + j * 16 + c];
  unsigned long long* m = (unsigned long long*)smem;  // [2][128], reuse LDS
#pragma unroll
  for (int i = 0; i < 4; ++i) {
    float4 sx4 = *(const float4*)&sx2[rowpan + wm * 64 + i * 16 + q * 4];
#pragma unroll
    for (int r = 0; r < 4; ++r) {
      float sx = ((const float*)&sx4)[r];
      float bs = 3.402823466e38f;
      int bk = 0;
#pragma unroll
      for (int j = 0; j < 4; ++j) {  // ascending j -> ascending code
        float t1 = sx + se_j[j];            // fp32 round 1 (matches ref)
        float d = t1 - acc[i][j][r] * inv;  // exact mul, fp32 round 2
        if (d < bs) { bs = d; bk = colpan + wn * 64 + j * 16 + c; }
      }
#pragma unroll
      for (int off = 1; off < 16; off <<= 1) {  // reduce over c (q kept)
        float os = __shfl_xor(bs, off, 64);
        int ok = __shfl_xor(bk, off, 64);
        if (os < bs || (os == bs && ok < bk)) { bs = os; bk = ok; }
      }
      if (c == 0) {
        m[wn * 128 + wm * 64 + i * 16 + q * 4 + r] =
            ((unsigned long long)__float_as_uint(bs) << 32) |
            (unsigned long long)(unsigned int)bk;
      }
    }
  }
  __syncthreads();
  if (tid < 128) {  // merge 2 wn-candidates; u64 min == (min d, then min k)
    unsigned long long v = m[tid];
    unsigned long long o = m[128 + tid];
    if (o < v) v = o;
    atomicMin(&packed[rowpan + tid], v);
  }
}

// ---------------------------------------------------------------------------
// Unpack winner per row, histogram, gather codebook rows, STE output,
// per-wave double partials. (r4 version, unchanged)
__global__ __launch_bounds__(256) void k_gather(
    const float* __restrict__ X, const float* __restrict__ E,
    const unsigned long long* __restrict__ packed, float* __restrict__ outq,
    float* __restrict__ out_ind, int* __restrict__ counts,
    double* __restrict__ msep, double* __restrict__ distp) {
  __shared__ int sk[16];
  __shared__ float sd[16];
  int tid = threadIdx.x;
  if (tid < 16) {
    int row = blockIdx.x * 16 + tid;
    unsigned long long v = packed[row];
    int k = (int)(v & 0xFFFFFFFFull);
    sk[tid] = k;
    sd[tid] = __uint_as_float((unsigned int)(v >> 32));
    out_ind[row] = (float)k;
    atomicAdd(&counts[k], 1);
  }
  __syncthreads();
  int wave = tid >> 6, lane = tid & 63;
  double msum = 0.0, dsum = 0.0;
#pragma unroll
  for (int rr = 0; rr < 4; rr++) {
    int li = wave * 4 + rr;
    int b = blockIdx.x * 16 + li;
    int ind = sk[li];
    float4 x4 = ((const float4*)(X + (size_t)b * D_DIM))[lane];
    float4 q4 = ((const float4*)(E + (size_t)ind * D_DIM))[lane];
    float d0 = q4.x - x4.x, d1 = q4.y - x4.y, d2 = q4.z - x4.z, d3 = q4.w - x4.w;
    float4 o;
    o.x = x4.x + d0; o.y = x4.y + d1; o.z = x4.z + d2; o.w = x4.w + d3;
    ((float4*)(outq + (size_t)b * D_DIM))[lane] = o;
    float v = d0 * d0 + d1 * d1 + d2 * d2 + d3 * d3;
#pragma unroll
    for (int off = 32; off > 0; off >>= 1) v += __shfl_xor(v, off, 64);
    if (lane == 0) { msum += (double)v; dsum += (double)sd[li]; }
  }
  if (lane == 0) {
    int wg = blockIdx.x * 4 + wave;
    msep[wg] = msum;
    distp[wg] = dsum;
  }
}

// ---------------------------------------------------------------------------
__global__ __launch_bounds__(256) void k_final(
    const int* __restrict__ counts, const double* __restrict__ msep,
    const double* __restrict__ distp, float* __restrict__ out) {
  __shared__ double red[256];
  int t = threadIdx.x;

  double m = 0.0;
  for (int i = t; i < 8192; i += 256) m += msep[i];
  red[t] = m;
  __syncthreads();
  for (int s = 128; s > 0; s >>= 1) {
    if (t < s) red[t] += red[t + s];
    __syncthreads();
  }
  if (t == 0) {
    double mse = red[0] / ((double)B_ROWS * (double)D_DIM);
    out[OUT_VQ] = (float)(mse * 1.25);  // 0.25*commit + embed
  }
  __syncthreads();

  double d = 0.0;
  for (int i = t; i < 8192; i += 256) d += distp[i];
  red[t] = d;
  __syncthreads();
  for (int s = 128; s > 0; s >>= 1) {
    if (t < s) red[t] += red[t + s];
    __syncthreads();
  }
  if (t == 0) out[OUT_CM] = (float)(red[0] / (double)B_ROWS);
  __syncthreads();

  double e = 0.0;
  for (int k = t; k < K_CODES; k += 256) {
    float p = (float)counts[k] * (1.0f / 32768.0f);
    e += (double)(p * logf(p + 1e-10f));
  }
  red[t] = e;
  __syncthreads();
  for (int s = 128; s > 0; s >>= 1) {
    if (t < s) red[t] += red[t + s];
    __syncthreads();
  }
  if (t == 0) out[OUT_ENT] = (float)(-red[0]);
}

// ---------------------------------------------------------------------------
extern "C" void kernel_launch(void* const* d_in, const int* in_sizes, int n_in,
                              void* d_out, int out_size, void* d_ws,
                              size_t ws_size, hipStream_t stream) {
  const float* X = (const float*)d_in[0];  // latents [32768,256]
  const float* E = (const float*)d_in[1];  // embedding [2048,256]
  float* out = (float*)d_out;
  char* ws = (char*)d_ws;
  float* se2 = (float*)(ws + WS_SE2);
  float* sx2 = (float*)(ws + WS_SX2);
  int* counts = (int*)(ws + WS_CNT);
  unsigned long long* packed = (unsigned long long*)(ws + WS_PACK);
  double* msep = (double*)(ws + WS_MSEP);
  double* distp = (double*)(ws + WS_DISTP);
  _Float16* Bcat = (_Float16*)(ws + WS_BCAT);
  _Float16* Acat = (_Float16*)d_out;  // Q region; k_gather overwrites later

  static bool attr_done = false;
  if (!attr_done) {  // allow 64 KiB dynamic LDS for k_mfma2
    hipFuncSetAttribute((const void*)k_mfma2,
                        hipFuncAttributeMaxDynamicSharedMemorySize, 65536);
    attr_done = true;
  }

  k_init<<<8704, 256, 0, stream>>>(X, E, Acat, Bcat, sx2, se2, packed, counts);
  k_mfma2<<<4096, 256, 65536, stream>>>(Acat, Bcat, se2, sx2, packed);
  k_gather<<<B_ROWS / 16, 256, 0, stream>>>(X, E, packed, out + OUT_Q,
                                            out + OUT_IND, counts, msep, distp);
  k_final<<<1, 256, 0, stream>>>(counts, msep, distp, out);
}

// Round 9
// 258.560 us; speedup vs baseline: 2.3139x; 1.0501x over previous
//
#include <hip/hip_runtime.h>
#include <math.h>

#define B_ROWS 32768
#define D_DIM  256
#define K_CODES 2048

// d_out layout (float elements), reference return order:
// quantized_st [B,D], vq_loss, entropy, encoding_inds [B,1], cluster_metric
#define OUT_Q   0
#define OUT_VQ  8388608
#define OUT_ENT 8388609
#define OUT_IND 8388610
#define OUT_CM  8421378

// A_cat [32768][512] fp16 = 33.55 MB lives in the d_out Q region (exact fit);
// k_gather overwrites it with the real output afterwards.

// ws layout (bytes)
#define WS_SE2   0          // 2048 float
#define WS_SX2   8192       // 32768 float
#define WS_CNT   139264     // 2048 int   (zeroed in k_init)
#define WS_PACK  147456     // 32768 u64  (set to ~0 in k_init)
#define WS_MSEP  409600     // 8192 double
#define WS_DISTP 475136     // 8192 double
#define WS_BCAT  540672     // 2048 x 768 fp16 = 3 MB

typedef _Float16 f16x8 __attribute__((ext_vector_type(8)));
typedef float f32x4 __attribute__((ext_vector_type(4)));
typedef union { _Float16 h[4]; uint2 u2; } h4pack;

// ---------------------------------------------------------------------------
// Fused init (r4 version, unchanged).
__global__ __launch_bounds__(256) void k_init(
    const float* __restrict__ X, const float* __restrict__ E,
    _Float16* __restrict__ A, _Float16* __restrict__ Bc,
    float* __restrict__ sx2, float* __restrict__ se2,
    unsigned long long* __restrict__ packed, int* __restrict__ counts) {
  int w = threadIdx.x >> 6, lane = threadIdx.x & 63;
  if (blockIdx.x < 8192) {
    int row = blockIdx.x * 4 + w;
    float4 v = ((const float4*)(X + (size_t)row * D_DIM))[lane];
    float s = v.x * v.x + v.y * v.y + v.z * v.z + v.w * v.w;
#pragma unroll
    for (int off = 32; off > 0; off >>= 1) s += __shfl_xor(s, off, 64);
    if (lane == 0) { sx2[row] = s; packed[row] = ~0ull; }
    h4pack hi, lo;
    hi.h[0] = (_Float16)v.x; hi.h[1] = (_Float16)v.y;
    hi.h[2] = (_Float16)v.z; hi.h[3] = (_Float16)v.w;
    lo.h[0] = (_Float16)((v.x - (float)hi.h[0]) * 4096.0f);
    lo.h[1] = (_Float16)((v.y - (float)hi.h[1]) * 4096.0f);
    lo.h[2] = (_Float16)((v.z - (float)hi.h[2]) * 4096.0f);
    lo.h[3] = (_Float16)((v.w - (float)hi.h[3]) * 4096.0f);
    *(uint2*)&A[(size_t)row * 512 + 4 * lane] = hi.u2;
    *(uint2*)&A[(size_t)row * 512 + 256 + 4 * lane] = lo.u2;
  } else {
    int bb = blockIdx.x - 8192;
    int row = bb * 4 + w;
    if (threadIdx.x < 4) counts[bb * 4 + threadIdx.x] = 0;
    float4 v = ((const float4*)(E + (size_t)row * D_DIM))[lane];
    float s = v.x * v.x + v.y * v.y + v.z * v.z + v.w * v.w;
#pragma unroll
    for (int off = 32; off > 0; off >>= 1) s += __shfl_xor(s, off, 64);
    if (lane == 0) se2[row] = s;
    const float S = 4194304.0f;       // 2^22
    const float SH = 0.000244140625f; // 2^-12
    float e0 = v.x * S, e1 = v.y * S, e2 = v.z * S, e3 = v.w * S;
    h4pack b1, b2, b3;
    b1.h[0] = (_Float16)e0; b1.h[1] = (_Float16)e1;
    b1.h[2] = (_Float16)e2; b1.h[3] = (_Float16)e3;
    b2.h[0] = (_Float16)((float)b1.h[0] * SH);
    b2.h[1] = (_Float16)((float)b1.h[1] * SH);
    b2.h[2] = (_Float16)((float)b1.h[2] * SH);
    b2.h[3] = (_Float16)((float)b1.h[3] * SH);
    b3.h[0] = (_Float16)(e0 - (float)b1.h[0]);
    b3.h[1] = (_Float16)(e1 - (float)b1.h[1]);
    b3.h[2] = (_Float16)(e2 - (float)b1.h[2]);
    b3.h[3] = (_Float16)(e3 - (float)b1.h[3]);
    *(uint2*)&Bc[(size_t)row * 768 + 4 * lane] = b1.u2;
    *(uint2*)&Bc[(size_t)row * 768 + 256 + 4 * lane] = b2.u2;
    *(uint2*)&Bc[(size_t)row * 768 + 512 + 4 * lane] = b3.u2;
  }
}

// ---------------------------------------------------------------------------
// 256x256-tile MFMA GEMM + argmin.  EXACT r4 structure (passed, 152 us GEMM)
// with ONE change: MFMA loop order kk-OUTERMOST.  All prior rounds had kk
// innermost, so every consecutive MFMA pair hit the SAME acc register
// (kk=0,1 of acc[ii][jj]) -> each 2nd MFMA pays full result latency (~20cyc)
// instead of the ~5cyc issue slot; with 2 waves/SIMD nothing fills the
// bubble (the shared 26-30% MfmaUtil plateau across r0-r7).  kk-outer gives
// 8 independent MFMAs between reuses of any acc register, zero reg cost.
// Per-fragment k-order (kk=0 then kk=1 for every acc[i][j]) is UNCHANGED ->
// bit-exact accumulation.  (r8's k_gather fusion removed: isolate this
// single variable; r8's container failure is then attributable.)
#define BAR()  __builtin_amdgcn_s_barrier()
#define SB0()  __builtin_amdgcn_sched_barrier(0)
#define WLGKM(n)                                                 \
  do {                                                           \
    asm volatile("s_waitcnt lgkmcnt(" #n ")" ::: "memory");      \
    SB0();                                                       \
  } while (0)
#define DSR(dst, a, o) \
  asm volatile("ds_read_b128 %0, %1 offset:" o : "=v"(dst) : "v"(a))

#define MFMA_QUAD(I0, J0, AF, BF)                                            \
  do {                                                                       \
    __builtin_amdgcn_s_setprio(1);                                           \
    _Pragma("unroll") for (int kk = 0; kk < 2; ++kk) {                       \
      _Pragma("unroll") for (int ii = 0; ii < 4; ++ii) {                     \
        _Pragma("unroll") for (int jj = 0; jj < 2; ++jj) {                   \
          acc[(I0) + ii][(J0) + jj] =                                        \
              __builtin_amdgcn_mfma_f32_16x16x32_f16(                        \
                  (AF)[ii * 2 + kk], (BF)[jj * 2 + kk],                      \
                  acc[(I0) + ii][(J0) + jj], 0, 0, 0);                       \
        }                                                                    \
      }                                                                      \
    }                                                                        \
    __builtin_amdgcn_s_setprio(0);                                           \
  } while (0)

__global__ __launch_bounds__(512, 2) void k_mfma2(
    const _Float16* __restrict__ A, const _Float16* __restrict__ Bc,
    const float* __restrict__ se2, const float* __restrict__ sx2,
    unsigned long long* __restrict__ packed) {
  extern __shared__ char smem[];  // 131072 B
  const int tid = threadIdx.x;
  const int w = tid >> 6, lane = tid & 63;
  const int wm = w >> 2, wn = w & 3;     // wave tile: rows wm*128, cols wn*64
  const int q = lane >> 4, c = lane & 15;
  const int rowb = blockIdx.x & 127, colb = blockIdx.x >> 7;
  const int rowpan = rowb * 256, colpan = colb * 256;
  const int rsel = lane >> 3;                      // staging: row-within-8
  const int chunkb = ((lane & 7) ^ rsel) * 16;     // inverse-swizzled src 16B
  const int rswz = c & 7;                          // read-side swizzle key

  const char* Abase = (const char*)A;
  const char* Bbase = (const char*)Bc;

  // g->(hh,ss): 0:A(0,0) 1:B(0,0) 2:B(0,1) 3:B(1,0) 4:B(1,1) 5:A(1,0)
  // 6:A(0,1) 7:A(1,1)
  auto issue = [&](int tt, int g, int bsel) {
    const int hh = (g == 3 || g == 4 || g == 5 || g == 7) ? 1 : 0;
    const int ss = (g == 2 || g == 4 || g == 6 || g == 7) ? 1 : 0;
    const int rl = hh * 128 + ss * 64 + w * 8 + rsel;
    const char* src;
    char* dst;
    if (g == 0 || g >= 5) {
      // A k-map (bytes/row of 1024): t<4 -> hi, 4..7 -> lo, 8..11 -> hi again
      int aoff = (tt & 3) * 128 + (((tt >> 2) == 1) ? 512 : 0);
      src = Abase + ((size_t)(rowpan + rl) << 10) + aoff + chunkb;
      dst = smem + bsel * 32768 + hh * 16384 + ss * 8192 + w * 1024;
    } else {
      src = Bbase + (size_t)(colpan + rl) * 1536 + tt * 128 + chunkb;
      dst = smem + 65536 + bsel * 32768 + hh * 16384 + ss * 8192 + w * 1024;
    }
    __builtin_amdgcn_global_load_lds(
        (const __attribute__((address_space(1))) unsigned int*)src,
        (__attribute__((address_space(3))) unsigned int*)dst, 16, 0, 0);
  };

  f32x4 acc[8][4];
#pragma unroll
  for (int i = 0; i < 8; ++i)
#pragma unroll
    for (int j = 0; j < 4; ++j) acc[i][j] = (f32x4){0.f, 0.f, 0.f, 0.f};

  // per-lane LDS byte addresses for asm ds_read_b128 (swizzled slots)
  const unsigned ldsA = (unsigned)(uintptr_t)smem + (unsigned)((wm * 128 + c) * 128);
  const unsigned ldsB = (unsigned)(uintptr_t)smem + 65536u +
                        (unsigned)((wn * 64 + c) * 128);
  const unsigned sl0 = (unsigned)(((0 * 4 + q) ^ rswz) * 16);
  const unsigned sl1 = (unsigned)(((1 * 4 + q) ^ rswz) * 16);

  // prologue: stage tile 0 fully, drain own DMA, publish via barrier
#pragma unroll
  for (int g = 0; g < 8; ++g) issue(0, g, 0);
  asm volatile("s_waitcnt vmcnt(0)" ::: "memory");
  BAR();

  f16x8 af[8], bf01[4], bf23[4];

#pragma unroll 2
  for (int t = 0; t < 12; ++t) {
    const int bsel = t & 1;
    const bool pre = (t < 11);
    const unsigned aA0 = ldsA + (unsigned)(bsel * 32768) + sl0;
    const unsigned aA1 = ldsA + (unsigned)(bsel * 32768) + sl1;
    const unsigned aB0 = ldsB + (unsigned)(bsel * 32768) + sl0;
    const unsigned aB1 = ldsB + (unsigned)(bsel * 32768) + sl1;

    // all 8 DMA issues for t+1 at tile start -> full tile of latency slack
    if (pre) {
#pragma unroll
      for (int g = 0; g < 8; ++g) issue(t + 1, g, bsel ^ 1);
    }

    // burst 1: A i-lo half (8) + all B (8); waves pipeline freely from here
    DSR(af[0], aA0, "0");    DSR(af[1], aA1, "0");
    DSR(af[2], aA0, "2048"); DSR(af[3], aA1, "2048");
    DSR(af[4], aA0, "4096"); DSR(af[5], aA1, "4096");
    DSR(af[6], aA0, "6144"); DSR(af[7], aA1, "6144");
    DSR(bf01[0], aB0, "0");    DSR(bf01[1], aB1, "0");
    DSR(bf01[2], aB0, "2048"); DSR(bf01[3], aB1, "2048");
    DSR(bf23[0], aB0, "4096"); DSR(bf23[1], aB1, "4096");
    DSR(bf23[2], aB0, "6144"); DSR(bf23[3], aB1, "6144");

    WLGKM(4);                 // af + bf01 resident (bf23 may still fly)
    MFMA_QUAD(0, 0, af, bf01);
    WLGKM(0);                 // bf23 resident (drained under Q0's MFMAs)
    MFMA_QUAD(0, 2, af, bf23);

    // A i-hi half reuses af regs (Q0/Q1 MFMAs already consumed old values);
    // these reads drain under Q1's MFMA execution.
    DSR(af[0], aA0, "8192");  DSR(af[1], aA1, "8192");
    DSR(af[2], aA0, "10240"); DSR(af[3], aA1, "10240");
    DSR(af[4], aA0, "12288"); DSR(af[5], aA1, "12288");
    DSR(af[6], aA0, "14336"); DSR(af[7], aA1, "14336");
    WLGKM(0);
    MFMA_QUAD(4, 2, af, bf23);
    MFMA_QUAD(4, 0, af, bf01);

    // boundary: drain OWN DMA first, then barrier publishes all waves'
    // LDS-DMA writes (wait-before-barrier; wait-after was r3's race).
    if (pre) {
      asm volatile("s_waitcnt vmcnt(0)" ::: "memory");
      BAR();
    }
  }

  __syncthreads();  // full fence before epilogue LDS reuse

  // ---- epilogue: identical dist math / tie rules as previous rounds ----
  const float inv = 4.76837158203125e-07f;  // 2^-21, exact pow2
  float se_j[4];
#pragma unroll
  for (int j = 0; j < 4; ++j) se_j[j] = se2[colpan + wn * 64 + j * 16 + c];
  unsigned long long* m = (unsigned long long*)smem;  // [4][256], reuse LDS
#pragma unroll
  for (int i = 0; i < 8; ++i) {
    float4 sx4 = *(const float4*)&sx2[rowpan + wm * 128 + i * 16 + q * 4];
#pragma unroll
    for (int r = 0; r < 4; ++r) {
      float sx = ((const float*)&sx4)[r];
      float bs = 3.402823466e38f;
      int bk = 0;
#pragma unroll
      for (int j = 0; j < 4; ++j) {  // ascending j -> ascending code
        float t1 = sx + se_j[j];            // fp32 round 1 (matches ref)
        float d = t1 - acc[i][j][r] * inv;  // exact mul, fp32 round 2
        if (d < bs) { bs = d; bk = colpan + wn * 64 + j * 16 + c; }
      }
#pragma unroll
      for (int off = 1; off < 16; off <<= 1) {  // reduce over c (q kept)
        float os = __shfl_xor(bs, off, 64);
        int ok = __shfl_xor(bk, off, 64);
        if (os < bs || (os == bs && ok < bk)) { bs = os; bk = ok; }
      }
      if (c == 0) {
        m[wn * 256 + wm * 128 + i * 16 + q * 4 + r] =
            ((unsigned long long)__float_as_uint(bs) << 32) |
            (unsigned long long)(unsigned int)bk;
      }
    }
  }
  __syncthreads();
  if (tid < 256) {  // merge 4 wn-candidates; u64 min == (min d, then min k)
    unsigned long long v = m[tid];
#pragma unroll
    for (int mm = 1; mm < 4; ++mm) {
      unsigned long long o = m[mm * 256 + tid];
      if (o < v) v = o;
    }
    atomicMin(&packed[rowpan + tid], v);
  }
}

// ---------------------------------------------------------------------------
// Unpack winner per row, histogram, gather codebook rows, STE output,
// per-wave double partials. (r4 version, unchanged)
__global__ __launch_bounds__(256) void k_gather(
    const float* __restrict__ X, const float* __restrict__ E,
    const unsigned long long* __restrict__ packed, float* __restrict__ outq,
    float* __restrict__ out_ind, int* __restrict__ counts,
    double* __restrict__ msep, double* __restrict__ distp) {
  __shared__ int sk[16];
  __shared__ float sd[16];
  int tid = threadIdx.x;
  if (tid < 16) {
    int row = blockIdx.x * 16 + tid;
    unsigned long long v = packed[row];
    int k = (int)(v & 0xFFFFFFFFull);
    sk[tid] = k;
    sd[tid] = __uint_as_float((unsigned int)(v >> 32));
    out_ind[row] = (float)k;
    atomicAdd(&counts[k], 1);
  }
  __syncthreads();
  int wave = tid >> 6, lane = tid & 63;
  double msum = 0.0, dsum = 0.0;
#pragma unroll
  for (int rr = 0; rr < 4; rr++) {
    int li = wave * 4 + rr;
    int b = blockIdx.x * 16 + li;
    int ind = sk[li];
    float4 x4 = ((const float4*)(X + (size_t)b * D_DIM))[lane];
    float4 q4 = ((const float4*)(E + (size_t)ind * D_DIM))[lane];
    float d0 = q4.x - x4.x, d1 = q4.y - x4.y, d2 = q4.z - x4.z, d3 = q4.w - x4.w;
    float4 o;
    o.x = x4.x + d0; o.y = x4.y + d1; o.z = x4.z + d2; o.w = x4.w + d3;
    ((float4*)(outq + (size_t)b * D_DIM))[lane] = o;
    float v = d0 * d0 + d1 * d1 + d2 * d2 + d3 * d3;
#pragma unroll
    for (int off = 32; off > 0; off >>= 1) v += __shfl_xor(v, off, 64);
    if (lane == 0) { msum += (double)v; dsum += (double)sd[li]; }
  }
  if (lane == 0) {
    int wg = blockIdx.x * 4 + wave;
    msep[wg] = msum;
    distp[wg] = dsum;
  }
}

// ---------------------------------------------------------------------------
__global__ __launch_bounds__(256) void k_final(
    const int* __restrict__ counts, const double* __restrict__ msep,
    const double* __restrict__ distp, float* __restrict__ out) {
  __shared__ double red[256];
  int t = threadIdx.x;

  double m = 0.0;
  for (int i = t; i < 8192; i += 256) m += msep[i];
  red[t] = m;
  __syncthreads();
  for (int s = 128; s > 0; s >>= 1) {
    if (t < s) red[t] += red[t + s];
    __syncthreads();
  }
  if (t == 0) {
    double mse = red[0] / ((double)B_ROWS * (double)D_DIM);
    out[OUT_VQ] = (float)(mse * 1.25);  // 0.25*commit + embed
  }
  __syncthreads();

  double d = 0.0;
  for (int i = t; i < 8192; i += 256) d += distp[i];
  red[t] = d;
  __syncthreads();
  for (int s = 128; s > 0; s >>= 1) {
    if (t < s) red[t] += red[t + s];
    __syncthreads();
  }
  if (t == 0) out[OUT_CM] = (float)(red[0] / (double)B_ROWS);
  __syncthreads();

  double e = 0.0;
  for (int k = t; k < K_CODES; k += 256) {
    float p = (float)counts[k] * (1.0f / 32768.0f);
    e += (double)(p * logf(p + 1e-10f));
  }
  red[t] = e;
  __syncthreads();
  for (int s = 128; s > 0; s >>= 1) {
    if (t < s) red[t] += red[t + s];
    __syncthreads();
  }
  if (t == 0) out[OUT_ENT] = (float)(-red[0]);
}

// ---------------------------------------------------------------------------
extern "C" void kernel_launch(void* const* d_in, const int* in_sizes, int n_in,
                              void* d_out, int out_size, void* d_ws,
                              size_t ws_size, hipStream_t stream) {
  const float* X = (const float*)d_in[0];  // latents [32768,256]
  const float* E = (const float*)d_in[1];  // embedding [2048,256]
  float* out = (float*)d_out;
  char* ws = (char*)d_ws;
  float* se2 = (float*)(ws + WS_SE2);
  float* sx2 = (float*)(ws + WS_SX2);
  int* counts = (int*)(ws + WS_CNT);
  unsigned long long* packed = (unsigned long long*)(ws + WS_PACK);
  double* msep = (double*)(ws + WS_MSEP);
  double* distp = (double*)(ws + WS_DISTP);
  _Float16* Bcat = (_Float16*)(ws + WS_BCAT);
  _Float16* Acat = (_Float16*)d_out;  // Q region; k_gather overwrites later

  static bool attr_done = false;
  if (!attr_done) {  // allow 128 KiB dynamic LDS for k_mfma2
    hipFuncSetAttribute((const void*)k_mfma2,
                        hipFuncAttributeMaxDynamicSharedMemorySize, 131072);
    attr_done = true;
  }

  k_init<<<8704, 256, 0, stream>>>(X, E, Acat, Bcat, sx2, se2, packed, counts);
  k_mfma2<<<1024, 512, 131072, stream>>>(Acat, Bcat, se2, sx2, packed);
  k_gather<<<B_ROWS / 16, 256, 0, stream>>>(X, E, packed, out + OUT_Q,
                                            out + OUT_IND, counts, msep, distp);
  k_final<<<1, 256, 0, stream>>>(counts, msep, distp, out);
}